// Round 8
// baseline (409.969 us; speedup 1.0000x reference)
//
#include <hip/hip_runtime.h>
#include <stdint.h>

#define BB 4
#define SDIM 128
#define S2 (SDIM*SDIM)          // 16384
#define S3 ((size_t)SDIM*S2)    // 2097152

typedef float vf4 __attribute__((ext_vector_type(4)));

// Per-wave probe: detect bool storage width (1B vs 4B) from structure
// (valid is a prefix of >=64 trues; element S-1 is always false), then
// return len[b] = popcount of the valid prefix. All 64 lanes participate.
__device__ __forceinline__ int probe_len(const void* em, int b, int lane) {
    const unsigned char* p8 = (const unsigned char*)em;
    const int* p32 = (const int*)em;
    const int t0 = lane, t1 = lane + 64;
    const size_t i0 = (size_t)b*S2 + (size_t)t0*SDIM + t0;
    const size_t i1 = (size_t)b*S2 + (size_t)t1*SDIM + t1;
    const unsigned char a0 = p8[i0], a1 = p8[i1];
    const bool ok = (a0 != 0) && (t1 != SDIM-1 || a1 == 0);
    const unsigned long long mok = __ballot(ok);
    const bool use8 = (mok == ~0ull);   // wave-uniform
    int v0, v1;
    if (use8) { v0 = (a0 != 0); v1 = (a1 != 0); }
    else      { v0 = (p32[i0] != 0); v1 = (p32[i1] != 0); }
    return __popcll(__ballot(v0)) + __popcll(__ballot(v1));
}

__device__ __forceinline__ float sigf(float x) { return 1.f / (1.f + expf(-x)); }

// k_prep v9: 2048 blocks (full residency). Item = (b, i, yq), yq in [0,4).
// Strip yq covers j = i + g + 8*yq + 32*t (t=0..3) -> union over yq = all
// j-i in [0,128). Four partial buffers split0..3 summed in k_upd.
__global__ __launch_bounds__(256, 6) void k_prep(
    const float* __restrict__ s_edge, const float* __restrict__ s_const,
    const float* __restrict__ s_split, const void* __restrict__ em,
    float* __restrict__ q_edge, float* __restrict__ q_span,
    float* __restrict__ split0, float* __restrict__ split1,
    float* __restrict__ split2, float* __restrict__ split3,
    float* __restrict__ peA, float* __restrict__ peB,
    float* __restrict__ peTA, float* __restrict__ peTB,
    float* __restrict__ psA, float* __restrict__ psB) {
    const int gid = blockIdx.x;              // [0, 2048)
    const int yq = gid & 3, x = gid >> 2;    // x in [0,512)
    const int b = x >> 7, i = x & 127;
    const int tid = threadIdx.x, lane = tid & 63;
    const int len = probe_len(em, b, lane);
    const int lm1 = len - 1;
    const size_t vb = (size_t)b*S2;
    if (yq == 0 && tid < SDIM) {
        const size_t ro = vb + (size_t)i*SDIM + tid;
        const float qe = s_edge[ro];
        const float qs = (i <= tid) ? s_const[ro] : s_const[vb + (size_t)tid*SDIM + i];
        q_edge[ro] = qe;
        q_span[ro] = qs;
        const float se = sigf(qe), ss = sigf(qs);
        peA[ro] = se; peB[ro] = se;
        psA[ro] = ss; psB[ro] = ss;
        const size_t to = vb + (size_t)tid*SDIM + i;
        peTA[to] = se; peTB[to] = se;
    }
    const int g = tid >> 5;            // j-group 0..7
    const int kq = (tid & 31) * 4;     // k base
    vf4 acc = (vf4)0.f;
    if (i >= 1 && i < len && kq < len) {
        const float* base = s_split + (size_t)b*S3 + (size_t)i*S2;
        #pragma unroll
        for (int t = 0; t < 4; ++t) {
            const int j = i + g + 8*yq + 32*t;
            const int jc = min(j, lm1);
            const vf4 v = *(const vf4*)(base + (size_t)jc*SDIM + kq);
            const bool jb = (j < len);
            acc.x += (jb && j != kq+0) ? v.x : 0.f;
            acc.y += (jb && j != kq+1) ? v.y : 0.f;
            acc.z += (jb && j != kq+2) ? v.z : 0.f;
            acc.w += (jb && j != kq+3) ? v.w : 0.f;
        }
    }
    __shared__ float red[8][SDIM];
    *(vf4*)&red[g][kq] = acc;
    __syncthreads();
    if (tid < SDIM) {
        float s = 0.f;
        #pragma unroll
        for (int gg = 0; gg < 8; ++gg) s += red[gg][tid];
        float* out = (yq == 0) ? split0 : (yq == 1) ? split1
                   : (yq == 2) ? split2 : split3;
        out[vb + (size_t)i*SDIM + tid] = (tid >= 1 && tid < len) ? s : 0.f;
    }
}

// k_upd v9: EXACT-FIT PERSISTENT GRID. 2048 blocks x 4 waves = 32 waves/CU
// = 100% residency ceiling, zero block churn (all blocks resident from t=0;
// rounds 0-7 never exceeded 29% occupancy because 4096-8192 short blocks
// were fill-rate limited, and BW tracked occupancy ~50 GB/s per % across
// ALL rounds). Inner body = r2's proven math, plain compiler loads (TLP
// hides latency, as in the 6.3 TB/s copy kernel). Block = (part, b, row,
// half): processes two 32-row chunks => contiguous 32KB/tensor streams.
__global__ __launch_bounds__(256, 6) void k_upd(
    const float* __restrict__ s_sib, const float* __restrict__ s_cop,
    const float* __restrict__ s_grd, const float* __restrict__ s_ep,
    const float* __restrict__ s_hb,  const float* __restrict__ s_he,
    const float* __restrict__ peA, const float* __restrict__ peTA,
    const float* __restrict__ psA,
    const float* __restrict__ split0, const float* __restrict__ split1,
    const float* __restrict__ split2, const float* __restrict__ split3,
    const void* __restrict__ em,
    float* __restrict__ q_edge, float* __restrict__ q_span,
    float* __restrict__ peB, float* __restrict__ peTB, float* __restrict__ psB) {
    const int gid = blockIdx.x;          // [0, 2048)
    const int part = gid & 1;
    const int idx = gid >> 1;            // [0, 1024)
    const int b = idx >> 8;              // [0, 4)
    const int row = (idx >> 1) & 127;
    const int hf = idx & 1;              // which 64-row half
    const int tid = threadIdx.x, wave = tid >> 6, lane = tid & 63;
    const int half = lane >> 5, sq = (lane & 31) * 4;
    const int len = probe_len(em, b, lane);
    const int lm1 = len - 1;
    const int sqa = min(sq, lm1 & ~3);   // clamped column base (address only)
    const size_t vb = (size_t)b*S2;

    if (part == 0) {
        const int h = row;
        if (h >= len) return;
        const size_t tb = (size_t)b*S3 + (size_t)h*S2;
        const size_t hrow = vb + (size_t)h*SDIM;
        const vf4 pe4 = *(const vf4*)(peA + hrow + sqa);
        for (int sub = 0; sub < 2; ++sub) {
            const int m0 = hf*64 + sub*32;
            if (m0 >= len) break;
            int mr[4];
            vf4 sib[4], cop[4], grd[4], epv[4], pet[4], psv[4];
            float qo[4];
            #pragma unroll
            for (int it = 0; it < 4; ++it) {
                const int m = m0 + 8*it + 2*wave + half;
                mr[it] = m;
                const int mc = min(m, lm1);    // clamped row (address only)
                const size_t ro = tb + (size_t)mc*SDIM + sqa;
                sib[it] = *(const vf4*)(s_sib + ro);
                cop[it] = *(const vf4*)(s_cop + ro);
                grd[it] = *(const vf4*)(s_grd + ro);
                epv[it] = *(const vf4*)(s_ep  + ro);
                const size_t vo = vb + (size_t)mc*SDIM + sqa;
                pet[it] = *(const vf4*)(peTA + vo);
                psv[it] = *(const vf4*)(psA  + vo);
                qo[it]  = q_edge[hrow + mc];
            }
            #pragma unroll
            for (int it = 0; it < 4; ++it) {
                const int m = mr[it];
                const bool mv = (m < len);
                float r = 0.f;
                #define TERM(C, F) { const int s = sq + C;                               \
                    const bool bs = mv && (s < len) && (m != s);                         \
                    const float fem = (bs && (h != s)) ? 1.f : 0.f;                      \
                    const float fnc = (bs && ((m >= h && s >= h) || (m <= h && s <= h))) \
                                      ? 1.f : 0.f;                                       \
                    r += fem * (sib[it].F*pe4.F + cop[it].F*pet[it].F + grd[it].F*psv[it].F) \
                       + fnc * (epv[it].F*psv[it].F); }
                TERM(0, x) TERM(1, y) TERM(2, z) TERM(3, w)
                #undef TERM
                r += __shfl_xor(r, 16); r += __shfl_xor(r, 8); r += __shfl_xor(r, 4);
                r += __shfl_xor(r, 2);  r += __shfl_xor(r, 1);
                if ((lane & 31) == 0 && mv) {
                    const float qn = qo[it] + r;
                    q_edge[hrow + m] = qn;
                    const float sg = sigf(qn);
                    peB[hrow + m] = sg;
                    peTB[vb + (size_t)m*SDIM + h] = sg;
                }
            }
        }
    } else {
        const int i = row;
        if (i < 1 || i >= len) return;
        const size_t irow = vb + (size_t)i*SDIM;
        const vf4 peTi4 = *(const vf4*)(peTA + irow + sqa);
        for (int sub = 0; sub < 2; ++sub) {
            const int j0 = hf*64 + sub*32;
            if (j0 >= len) break;
            int jr[4];
            vf4 hb[4], he[4], ptj[4];
            float qs[4], pq[4], sA[4], sB[4], sC[4], sD[4];
            #pragma unroll
            for (int it = 0; it < 4; ++it) {
                const int j = j0 + 8*it + 2*wave + half;
                jr[it] = j;
                const int jc = min(j, lm1);    // clamped row (address only)
                hb[it]  = *(const vf4*)(s_hb + (size_t)b*S3 + (size_t)i*S2 + (size_t)jc*SDIM + sqa);
                he[it]  = *(const vf4*)(s_he + (size_t)b*S3 + (size_t)jc*S2 + (size_t)i*SDIM + sqa);
                ptj[it] = *(const vf4*)(peTA + vb + (size_t)jc*SDIM + sqa);
                qs[it]  = q_span[irow + jc];
                pq[it]  = psA[irow + jc];
                sA[it]  = split0[irow + jc];
                sB[it]  = split1[irow + jc];
                sC[it]  = split2[irow + jc];
                sD[it]  = split3[irow + jc];
            }
            #pragma unroll
            for (int it = 0; it < 4; ++it) {
                const int j = jr[it];
                const bool act = (j > i) && (j < len);
                float r = 0.f;
                #define TERM(C, F) { const int s = sq + C;                               \
                    const float f = (act && s >= 1 && s < len && (s < i || s > j))       \
                                    ? 1.f : 0.f;                                         \
                    r += f * (hb[it].F*peTi4.F + he[it].F*ptj[it].F); }
                TERM(0, x) TERM(1, y) TERM(2, z) TERM(3, w)
                #undef TERM
                r += __shfl_xor(r, 16); r += __shfl_xor(r, 8); r += __shfl_xor(r, 4);
                r += __shfl_xor(r, 2);  r += __shfl_xor(r, 1);
                if ((lane & 31) == 0 && j >= 1 && j < len) {
                    const float qn = qs[it] + r
                                   + pq[it] * (sA[it] + sB[it] + sC[it] + sD[it]);
                    q_span[irow + j] = qn;
                    psB[irow + j] = sigf(qn);
                }
            }
        }
    }
}

extern "C" void kernel_launch(void* const* d_in, const int* in_sizes, int n_in,
                              void* d_out, int out_size, void* d_ws, size_t ws_size,
                              hipStream_t stream) {
    const float* s_edge  = (const float*)d_in[0];
    const float* s_const = (const float*)d_in[1];
    const float* s_sib   = (const float*)d_in[2];
    const float* s_cop   = (const float*)d_in[3];
    const float* s_grd   = (const float*)d_in[4];
    const float* s_ep    = (const float*)d_in[5];
    const float* s_split = (const float*)d_in[6];
    const float* s_hb    = (const float*)d_in[7];
    const float* s_he    = (const float*)d_in[8];
    const void*  em      = d_in[9];
    (void)in_sizes; (void)n_in; (void)out_size; (void)ws_size;

    float* q_edge = (float*)d_out;
    float* q_span = q_edge + (size_t)BB * S2;

    char* ws = (char*)d_ws;
    const size_t SZ = (size_t)BB * S2 * sizeof(float);   // 256 KiB
    float* split0 = (float*)(ws);
    float* split1 = (float*)(ws + 1*SZ);
    float* split2 = (float*)(ws + 2*SZ);
    float* split3 = (float*)(ws + 3*SZ);
    float* peA    = (float*)(ws + 4*SZ);
    float* peTA   = (float*)(ws + 5*SZ);
    float* psA    = (float*)(ws + 6*SZ);
    float* peB    = (float*)(ws + 7*SZ);
    float* peTB   = (float*)(ws + 8*SZ);
    float* psB    = (float*)(ws + 9*SZ);

    hipLaunchKernelGGL(k_prep, dim3(2048), dim3(256), 0, stream,
                       s_edge, s_const, s_split, em, q_edge, q_span,
                       split0, split1, split2, split3,
                       peA, peB, peTA, peTB, psA, psB);
    for (int it = 0; it < 3; ++it) {
        const int s = it & 1;
        const float* peR  = s ? peB  : peA;
        const float* peTR = s ? peTB : peTA;
        const float* psR  = s ? psB  : psA;
        float* peW  = s ? peA  : peB;
        float* peTW = s ? peTA : peTB;
        float* psW  = s ? psA  : psB;
        hipLaunchKernelGGL(k_upd, dim3(2048), dim3(256), 0, stream,
                           s_sib, s_cop, s_grd, s_ep, s_hb, s_he,
                           peR, peTR, psR, split0, split1, split2, split3, em,
                           q_edge, q_span, peW, peTW, psW);
    }
}

// Round 9
// 297.015 us; speedup vs baseline: 1.3803x; 1.3803x over previous
//
#include <hip/hip_runtime.h>
#include <stdint.h>

#define BB 4
#define SDIM 128
#define S2 (SDIM*SDIM)          // 16384
#define S3 ((size_t)SDIM*S2)    // 2097152

typedef float vf4 __attribute__((ext_vector_type(4)));

// Per-wave probe: detect bool storage width (1B vs 4B) from structure
// (valid is a prefix of >=64 trues; element S-1 is always false), then
// return len[b] = popcount of the valid prefix. All 64 lanes participate.
__device__ __forceinline__ int probe_len(const void* em, int b, int lane) {
    const unsigned char* p8 = (const unsigned char*)em;
    const int* p32 = (const int*)em;
    const int t0 = lane, t1 = lane + 64;
    const size_t i0 = (size_t)b*S2 + (size_t)t0*SDIM + t0;
    const size_t i1 = (size_t)b*S2 + (size_t)t1*SDIM + t1;
    const unsigned char a0 = p8[i0], a1 = p8[i1];
    const bool ok = (a0 != 0) && (t1 != SDIM-1 || a1 == 0);
    const unsigned long long mok = __ballot(ok);
    const bool use8 = (mok == ~0ull);   // wave-uniform
    int v0, v1;
    if (use8) { v0 = (a0 != 0); v1 = (a1 != 0); }
    else      { v0 = (p32[i0] != 0); v1 = (p32[i1] != 0); }
    return __popcll(__ballot(v0)) + __popcll(__ballot(v1));
}

__device__ __forceinline__ float sigf(float x) { return 1.f / (1.f + expf(-x)); }

// k_prep v10: 2048 blocks (exact-fit). Item = (b, i, yq), yq in [0,4).
// Strip yq covers j = i + g + 8*yq + 32*t (t=0..3). Four partial buffers
// split0..3 summed in k_upd. NO launch-bounds cap (r8's cap spilled: VGPR 40,
// +120 MB scratch traffic).
__global__ __launch_bounds__(256) void k_prep(
    const float* __restrict__ s_edge, const float* __restrict__ s_const,
    const float* __restrict__ s_split, const void* __restrict__ em,
    float* __restrict__ q_edge, float* __restrict__ q_span,
    float* __restrict__ split0, float* __restrict__ split1,
    float* __restrict__ split2, float* __restrict__ split3,
    float* __restrict__ peA, float* __restrict__ peB,
    float* __restrict__ peTA, float* __restrict__ peTB,
    float* __restrict__ psA, float* __restrict__ psB) {
    const int gid = blockIdx.x;              // [0, 2048)
    const int yq = gid & 3, x = gid >> 2;    // x in [0,512)
    const int b = x >> 7, i = x & 127;
    const int tid = threadIdx.x, lane = tid & 63;
    const int len = probe_len(em, b, lane);
    const int lm1 = len - 1;
    const size_t vb = (size_t)b*S2;
    if (yq == 0 && tid < SDIM) {
        const size_t ro = vb + (size_t)i*SDIM + tid;
        const float qe = s_edge[ro];
        const float qs = (i <= tid) ? s_const[ro] : s_const[vb + (size_t)tid*SDIM + i];
        q_edge[ro] = qe;
        q_span[ro] = qs;
        const float se = sigf(qe), ss = sigf(qs);
        peA[ro] = se; peB[ro] = se;
        psA[ro] = ss; psB[ro] = ss;
        const size_t to = vb + (size_t)tid*SDIM + i;
        peTA[to] = se; peTB[to] = se;
    }
    const int g = tid >> 5;            // j-group 0..7
    const int kq = (tid & 31) * 4;     // k base
    vf4 acc = (vf4)0.f;
    if (i >= 1 && i < len && kq < len) {
        const float* base = s_split + (size_t)b*S3 + (size_t)i*S2;
        #pragma unroll
        for (int t = 0; t < 4; ++t) {
            const int j = i + g + 8*yq + 32*t;
            const int jc = min(j, lm1);
            const vf4 v = *(const vf4*)(base + (size_t)jc*SDIM + kq);
            const bool jb = (j < len);
            acc.x += (jb && j != kq+0) ? v.x : 0.f;
            acc.y += (jb && j != kq+1) ? v.y : 0.f;
            acc.z += (jb && j != kq+2) ? v.z : 0.f;
            acc.w += (jb && j != kq+3) ? v.w : 0.f;
        }
    }
    __shared__ float red[8][SDIM];
    *(vf4*)&red[g][kq] = acc;
    __syncthreads();
    if (tid < SDIM) {
        float s = 0.f;
        #pragma unroll
        for (int gg = 0; gg < 8; ++gg) s += red[gg][tid];
        float* out = (yq == 0) ? split0 : (yq == 1) ? split1
                   : (yq == 2) ? split2 : split3;
        out[vb + (size_t)i*SDIM + tid] = (tid >= 1 && tid < len) ? s : 0.f;
    }
}

// k_upd v10: PERSISTENT EXACT-FIT GRID-STRIDE. 2048 blocks x 4 waves = full
// device capacity at VGPR<=64 (r2's body compiled to VGPR 60 naturally).
// Each block strides over the 4096 r2-style work items (2 items/block),
// which also balances around dead rows (len<128): a dead item costs one
// probe. Evidence basis: BW tracked occupancy at ~50 GB/s per point across
// ALL of rounds 0-8 (r7 falsified per-wave depth; r8's cap-induced spills
// falsified forced low-VGPR). No caps, no spills, no churn. Body = r2's
// proven math, ping-pong sigmoid epilogue unchanged.
__global__ __launch_bounds__(256) void k_upd(
    const float* __restrict__ s_sib, const float* __restrict__ s_cop,
    const float* __restrict__ s_grd, const float* __restrict__ s_ep,
    const float* __restrict__ s_hb,  const float* __restrict__ s_he,
    const float* __restrict__ peA, const float* __restrict__ peTA,
    const float* __restrict__ psA,
    const float* __restrict__ split0, const float* __restrict__ split1,
    const float* __restrict__ split2, const float* __restrict__ split3,
    const void* __restrict__ em,
    float* __restrict__ q_edge, float* __restrict__ q_span,
    float* __restrict__ peB, float* __restrict__ peTB, float* __restrict__ psB) {
    const int tid = threadIdx.x, wave = tid >> 6, lane = tid & 63;
    const int half = lane >> 5, sq = (lane & 31) * 4;

    for (int wi = blockIdx.x; wi < 4096; wi += 2048) {
        const int y = wi >> 9;             // 0..7
        const int x = wi & 511;
        const int b = x >> 7, row = x & 127;
        const int len = probe_len(em, b, lane);
        const int lm1 = len - 1;
        const int sqa = min(sq, lm1 & ~3); // clamped column base (address only)
        const size_t vb = (size_t)b*S2;

        if (y < 4) {
            const int h = row;
            const int m0 = y * 32;
            if (h >= len || m0 >= len) continue;
            const size_t tb = (size_t)b*S3 + (size_t)h*S2;
            const size_t hrow = vb + (size_t)h*SDIM;
            const vf4 pe4 = *(const vf4*)(peA + hrow + sqa);
            int mr[4];
            vf4 sib[4], cop[4], grd[4], epv[4], pet[4], psv[4];
            float qo[4];
            #pragma unroll
            for (int it = 0; it < 4; ++it) {
                const int m = m0 + 8*it + 2*wave + half;
                mr[it] = m;
                const int mc = min(m, lm1);    // clamped row (address only)
                const size_t ro = tb + (size_t)mc*SDIM + sqa;
                sib[it] = *(const vf4*)(s_sib + ro);
                cop[it] = *(const vf4*)(s_cop + ro);
                grd[it] = *(const vf4*)(s_grd + ro);
                epv[it] = *(const vf4*)(s_ep  + ro);
                const size_t vo = vb + (size_t)mc*SDIM + sqa;
                pet[it] = *(const vf4*)(peTA + vo);
                psv[it] = *(const vf4*)(psA  + vo);
                qo[it]  = q_edge[hrow + mc];
            }
            #pragma unroll
            for (int it = 0; it < 4; ++it) {
                const int m = mr[it];
                const bool mv = (m < len);
                float r = 0.f;
                #define TERM(C, F) { const int s = sq + C;                               \
                    const bool bs = mv && (s < len) && (m != s);                         \
                    const float fem = (bs && (h != s)) ? 1.f : 0.f;                      \
                    const float fnc = (bs && ((m >= h && s >= h) || (m <= h && s <= h))) \
                                      ? 1.f : 0.f;                                       \
                    r += fem * (sib[it].F*pe4.F + cop[it].F*pet[it].F + grd[it].F*psv[it].F) \
                       + fnc * (epv[it].F*psv[it].F); }
                TERM(0, x) TERM(1, y) TERM(2, z) TERM(3, w)
                #undef TERM
                r += __shfl_xor(r, 16); r += __shfl_xor(r, 8); r += __shfl_xor(r, 4);
                r += __shfl_xor(r, 2);  r += __shfl_xor(r, 1);
                if ((lane & 31) == 0 && mv) {
                    const float qn = qo[it] + r;
                    q_edge[hrow + m] = qn;
                    const float sg = sigf(qn);
                    peB[hrow + m] = sg;
                    peTB[vb + (size_t)m*SDIM + h] = sg;
                }
            }
        } else {
            const int i = row;
            const int j0 = (y - 4) * 32;
            if (i < 1 || i >= len || j0 >= len) continue;
            const size_t irow = vb + (size_t)i*SDIM;
            const vf4 peTi4 = *(const vf4*)(peTA + irow + sqa);
            int jr[4];
            vf4 hb[4], he[4], ptj[4];
            float qs[4], pq[4], sA[4], sB[4], sC[4], sD[4];
            #pragma unroll
            for (int it = 0; it < 4; ++it) {
                const int j = j0 + 8*it + 2*wave + half;
                jr[it] = j;
                const int jc = min(j, lm1);    // clamped row (address only)
                hb[it]  = *(const vf4*)(s_hb + (size_t)b*S3 + (size_t)i*S2 + (size_t)jc*SDIM + sqa);
                he[it]  = *(const vf4*)(s_he + (size_t)b*S3 + (size_t)jc*S2 + (size_t)i*SDIM + sqa);
                ptj[it] = *(const vf4*)(peTA + vb + (size_t)jc*SDIM + sqa);
                qs[it]  = q_span[irow + jc];
                pq[it]  = psA[irow + jc];
                sA[it]  = split0[irow + jc];
                sB[it]  = split1[irow + jc];
                sC[it]  = split2[irow + jc];
                sD[it]  = split3[irow + jc];
            }
            #pragma unroll
            for (int it = 0; it < 4; ++it) {
                const int j = jr[it];
                const bool act = (j > i) && (j < len);
                float r = 0.f;
                #define TERM(C, F) { const int s = sq + C;                               \
                    const float f = (act && s >= 1 && s < len && (s < i || s > j))       \
                                    ? 1.f : 0.f;                                         \
                    r += f * (hb[it].F*peTi4.F + he[it].F*ptj[it].F); }
                TERM(0, x) TERM(1, y) TERM(2, z) TERM(3, w)
                #undef TERM
                r += __shfl_xor(r, 16); r += __shfl_xor(r, 8); r += __shfl_xor(r, 4);
                r += __shfl_xor(r, 2);  r += __shfl_xor(r, 1);
                if ((lane & 31) == 0 && j >= 1 && j < len) {
                    const float qn = qs[it] + r
                                   + pq[it] * (sA[it] + sB[it] + sC[it] + sD[it]);
                    q_span[irow + j] = qn;
                    psB[irow + j] = sigf(qn);
                }
            }
        }
    }
}

extern "C" void kernel_launch(void* const* d_in, const int* in_sizes, int n_in,
                              void* d_out, int out_size, void* d_ws, size_t ws_size,
                              hipStream_t stream) {
    const float* s_edge  = (const float*)d_in[0];
    const float* s_const = (const float*)d_in[1];
    const float* s_sib   = (const float*)d_in[2];
    const float* s_cop   = (const float*)d_in[3];
    const float* s_grd   = (const float*)d_in[4];
    const float* s_ep    = (const float*)d_in[5];
    const float* s_split = (const float*)d_in[6];
    const float* s_hb    = (const float*)d_in[7];
    const float* s_he    = (const float*)d_in[8];
    const void*  em      = d_in[9];
    (void)in_sizes; (void)n_in; (void)out_size; (void)ws_size;

    float* q_edge = (float*)d_out;
    float* q_span = q_edge + (size_t)BB * S2;

    char* ws = (char*)d_ws;
    const size_t SZ = (size_t)BB * S2 * sizeof(float);   // 256 KiB
    float* split0 = (float*)(ws);
    float* split1 = (float*)(ws + 1*SZ);
    float* split2 = (float*)(ws + 2*SZ);
    float* split3 = (float*)(ws + 3*SZ);
    float* peA    = (float*)(ws + 4*SZ);
    float* peTA   = (float*)(ws + 5*SZ);
    float* psA    = (float*)(ws + 6*SZ);
    float* peB    = (float*)(ws + 7*SZ);
    float* peTB   = (float*)(ws + 8*SZ);
    float* psB    = (float*)(ws + 9*SZ);

    hipLaunchKernelGGL(k_prep, dim3(2048), dim3(256), 0, stream,
                       s_edge, s_const, s_split, em, q_edge, q_span,
                       split0, split1, split2, split3,
                       peA, peB, peTA, peTB, psA, psB);
    for (int it = 0; it < 3; ++it) {
        const int s = it & 1;
        const float* peR  = s ? peB  : peA;
        const float* peTR = s ? peTB : peTA;
        const float* psR  = s ? psB  : psA;
        float* peW  = s ? peA  : peB;
        float* peTW = s ? peTA : peTB;
        float* psW  = s ? psA  : psB;
        hipLaunchKernelGGL(k_upd, dim3(2048), dim3(256), 0, stream,
                           s_sib, s_cop, s_grd, s_ep, s_hb, s_he,
                           peR, peTR, psR, split0, split1, split2, split3, em,
                           q_edge, q_span, peW, peTW, psW);
    }
}